// Round 6
// baseline (585.632 us; speedup 1.0000x reference)
//
#include <hip/hip_runtime.h>

// Problem constants (from reference)
#define NNZ_TOT    2097152
#define N_CELLS    4096
#define N_PRE      30000
#define NUM_HID    128
#define CHUNK      128                  // nnz per wave
#define N_WAVES    (NNZ_TOT / CHUNK)    // 16384 waves

// ---------------------------------------------------------------------------
// Precompute 1: g_arr[i] = gidx[xc[i]]  (fuse first indirection)
// ---------------------------------------------------------------------------
__global__ __launch_bounds__(256) void fuse_gidx_kernel(
    const int* __restrict__ xc, const int* __restrict__ gidx,
    int* __restrict__ g_arr)
{
    const int i = blockIdx.x * blockDim.x + threadIdx.x;
    if (i < NNZ_TOT) g_arr[i] = gidx[xc[i]];
}

// ---------------------------------------------------------------------------
// Precompute 2: bf16 copy of the embedding table (rows 512 B -> 256 B).
// ---------------------------------------------------------------------------
__device__ __forceinline__ unsigned short f2bf(float f) {
    union { float f; unsigned u; } c; c.f = f;
    unsigned u = c.u;
    u += 0x7fffu + ((u >> 16) & 1u);    // round-to-nearest-even
    return (unsigned short)(u >> 16);
}

__global__ __launch_bounds__(256) void convert_embs_kernel(
    const float* __restrict__ embs, unsigned short* __restrict__ ebf)
{
    const int i = blockIdx.x * blockDim.x + threadIdx.x;   // per 4 floats
    if (i * 4 < N_PRE * NUM_HID) {
        const float4 f = *reinterpret_cast<const float4*>(&embs[i * 4]);
        ushort4 o;
        o.x = f2bf(f.x); o.y = f2bf(f.y); o.z = f2bf(f.z); o.w = f2bf(f.w);
        *reinterpret_cast<ushort4*>(&ebf[i * 4]) = o;
    }
}

// ---------------------------------------------------------------------------
// Main kernel: one wave per 128-nnz chunk. Lane split: sub = lane&15 owns
// dims [sub*8, sub*8+8) (16 B bf16), quad = lane>>4 selects one of 4
// consecutive nnz -> ONE global_load_dwordx4 fetches 4 full embedding rows
// (2 cache lines per nnz vs 4 for fp32 float2 layout).
// NOTE R5 post-mortem: __launch_bounds__(256,8) capped VGPRs at 64 and
// spilled the gather buffers to scratch (WRITE_SIZE 1.1 GB). No min-wave
// cap here; kernel needs ~60-90 VGPRs and 4+ waves/SIMD is sufficient.
// Flush: direct atomicAdd from all 4 quads (4-way HW-serialized address
// collision) -- no DS/shuffle traffic; flushes are ~1 per wave.
// ---------------------------------------------------------------------------
__device__ __forceinline__ void fma_bf16x8(uint4 f, float vv, float acc[8]) {
    const unsigned uu[4] = { f.x, f.y, f.z, f.w };
    #pragma unroll
    for (int t = 0; t < 4; ++t) {
        const float lo = __uint_as_float(uu[t] << 16);
        const float hi = __uint_as_float(uu[t] & 0xffff0000u);
        acc[2 * t]     = fmaf(vv, lo, acc[2 * t]);
        acc[2 * t + 1] = fmaf(vv, hi, acc[2 * t + 1]);
    }
}

__device__ __forceinline__ void flush_acc(float* __restrict__ out, int row,
                                          int h8, float acc[8]) {
    float* o = &out[(long)row * NUM_HID + h8];
    #pragma unroll
    for (int k = 0; k < 8; ++k) {
        atomicAdd(o + k, acc[k]);
        acc[k] = 0.f;
    }
}

__global__ __launch_bounds__(256) void omics_bf16_kernel(
    const float*          __restrict__ xv,    // [NNZ] values
    const int*            __restrict__ xr,    // [NNZ] rows (sorted)
    const int*            __restrict__ g_arr, // [NNZ] fused gene ids
    const unsigned short* __restrict__ ebf,   // [N_PRE,128] bf16
    float*                __restrict__ out)   // [N_CELLS,128]
{
    const int wave = (blockIdx.x * blockDim.x + threadIdx.x) >> 6;
    const int lane = threadIdx.x & 63;
    const int sub  = lane & 15;
    const int quad = lane >> 4;
    const int base = __builtin_amdgcn_readfirstlane(wave * CHUNK);
    const int h8   = sub * 8;

    float acc[8] = {0.f, 0.f, 0.f, 0.f, 0.f, 0.f, 0.f, 0.f};

    const int rF = xr[base];
    const int rL = xr[base + CHUNK - 1];

    if (rF == rL) {
        // ---- fast path: whole chunk in one row (~75% of chunks) ----
        for (int it = 0; it < CHUNK; it += 16) {
            int g[16]; float v[16];
            #pragma unroll
            for (int j = 0; j < 16; ++j) {           // uniform -> s_load
                g[j] = g_arr[base + it + j];
                v[j] = xv[base + it + j];
            }
            uint4 f[4];
            #pragma unroll
            for (int u = 0; u < 4; ++u) {
                int gg = g[4 * u];
                gg = (quad == 1) ? g[4 * u + 1] : gg;
                gg = (quad == 2) ? g[4 * u + 2] : gg;
                gg = (quad == 3) ? g[4 * u + 3] : gg;
                f[u] = *reinterpret_cast<const uint4*>(
                    &ebf[(long)gg * NUM_HID + h8]);
            }
            #pragma unroll
            for (int u = 0; u < 4; ++u) {
                float vv = v[4 * u];
                vv = (quad == 1) ? v[4 * u + 1] : vv;
                vv = (quad == 2) ? v[4 * u + 2] : vv;
                vv = (quad == 3) ? v[4 * u + 3] : vv;
                fma_bf16x8(f[u], vv, acc);
            }
        }
        flush_acc(out, rF, h8, acc);
    } else {
        // ---- slow path: chunk crosses >=1 row boundary ----
        int cur = rF;
        for (int it = 0; it < CHUNK; it += 16) {
            const int i0 = base + it;
            const int rA = xr[i0];
            const int rB = xr[i0 + 15];
            if (rA == rB) {
                if (rA != cur) { flush_acc(out, cur, h8, acc); cur = rA; }
                int g[16]; float v[16];
                #pragma unroll
                for (int j = 0; j < 16; ++j) {
                    g[j] = g_arr[i0 + j];
                    v[j] = xv[i0 + j];
                }
                uint4 f[4];
                #pragma unroll
                for (int u = 0; u < 4; ++u) {
                    int gg = g[4 * u];
                    gg = (quad == 1) ? g[4 * u + 1] : gg;
                    gg = (quad == 2) ? g[4 * u + 2] : gg;
                    gg = (quad == 3) ? g[4 * u + 3] : gg;
                    f[u] = *reinterpret_cast<const uint4*>(
                        &ebf[(long)gg * NUM_HID + h8]);
                }
                #pragma unroll
                for (int u = 0; u < 4; ++u) {
                    float vv = v[4 * u];
                    vv = (quad == 1) ? v[4 * u + 1] : vv;
                    vv = (quad == 2) ? v[4 * u + 2] : vv;
                    vv = (quad == 3) ? v[4 * u + 3] : vv;
                    fma_bf16x8(f[u], vv, acc);
                }
            } else {
                // row boundary inside this 16-group (rare): element-wise,
                // quad 0 gathers alone; plain loop (no unroll -> no bloat)
                for (int j = 0; j < 16; ++j) {
                    const int r = xr[i0 + j];                 // uniform
                    if (r != cur) { flush_acc(out, cur, h8, acc); cur = r; }
                    if (quad == 0) {
                        const int   gg = g_arr[i0 + j];       // uniform
                        const float vv = xv[i0 + j];          // uniform
                        const uint4 f = *reinterpret_cast<const uint4*>(
                            &ebf[(long)gg * NUM_HID + h8]);
                        fma_bf16x8(f, vv, acc);
                    }
                }
            }
        }
        flush_acc(out, cur, h8, acc);
    }
}

// ---------------------------------------------------------------------------
// Fallback (ws too small): fp32 chunk kernel (R3/R4 style).
// ---------------------------------------------------------------------------
__device__ __forceinline__ void flush_row2(float* __restrict__ out, int row,
                                           int h, float2 acc) {
    float* o = &out[(long)row * NUM_HID + h];
    atomicAdd(o + 0, acc.x);
    atomicAdd(o + 1, acc.y);
}

template <bool PRE>
__global__ __launch_bounds__(256) void omics_fp32_kernel(
    const float* __restrict__ xv, const int* __restrict__ xr,
    const int* __restrict__ xc, const int* __restrict__ gidx,
    const int* __restrict__ g_arr, const float* __restrict__ embs,
    float* __restrict__ out)
{
    const int wave = (blockIdx.x * blockDim.x + threadIdx.x) >> 6;
    const int lane = threadIdx.x & 63;
    const int base = __builtin_amdgcn_readfirstlane(wave * CHUNK);
    const int h    = lane * 2;

    float2 acc = make_float2(0.f, 0.f);
    int cur = xr[base];
    for (int it = 0; it < CHUNK; it += 8) {
        const int i0 = base + it;
        #pragma unroll
        for (int j = 0; j < 8; ++j) {
            const int r = xr[i0 + j];
            if (r != cur) { flush_row2(out, cur, h, acc);
                            cur = r; acc = make_float2(0.f, 0.f); }
            const int   gg = PRE ? g_arr[i0 + j] : gidx[xc[i0 + j]];
            const float vv = xv[i0 + j];
            const float2 ff = *reinterpret_cast<const float2*>(
                &embs[(long)gg * NUM_HID + h]);
            acc.x = fmaf(vv, ff.x, acc.x);
            acc.y = fmaf(vv, ff.y, acc.y);
        }
    }
    flush_row2(out, cur, h, acc);
}

extern "C" void kernel_launch(void* const* d_in, const int* in_sizes, int n_in,
                              void* d_out, int out_size, void* d_ws, size_t ws_size,
                              hipStream_t stream) {
    const float* xv   = (const float*)d_in[0];
    const int*   xr   = (const int*)  d_in[1];
    const int*   xc   = (const int*)  d_in[2];
    const int*   gidx = (const int*)  d_in[3];
    const float* embs = (const float*)d_in[4];
    float*       out  = (float*)d_out;

    // Atomically accumulated -> zero first (harness poisons with 0xAA).
    hipMemsetAsync(out, 0, (size_t)out_size * sizeof(float), stream);

    const size_t g_bytes = (size_t)NNZ_TOT * sizeof(int);           // 8 MB
    const size_t e_bytes = (size_t)N_PRE * NUM_HID * 2;             // 7.7 MB
    const int    blocks  = (N_WAVES * 64) / 256;                    // 4096

    if (ws_size >= g_bytes + e_bytes) {
        int*            g_arr = (int*)d_ws;
        unsigned short* ebf   = (unsigned short*)((char*)d_ws + g_bytes);
        fuse_gidx_kernel<<<(NNZ_TOT + 255) / 256, 256, 0, stream>>>(
            xc, gidx, g_arr);
        convert_embs_kernel<<<(N_PRE * NUM_HID / 4 + 255) / 256, 256, 0, stream>>>(
            embs, ebf);
        omics_bf16_kernel<<<blocks, 256, 0, stream>>>(
            xv, xr, g_arr, ebf, out);
    } else if (ws_size >= g_bytes) {
        int* g_arr = (int*)d_ws;
        fuse_gidx_kernel<<<(NNZ_TOT + 255) / 256, 256, 0, stream>>>(
            xc, gidx, g_arr);
        omics_fp32_kernel<true><<<blocks, 256, 0, stream>>>(
            xv, xr, xc, gidx, g_arr, embs, out);
    } else {
        omics_fp32_kernel<false><<<blocks, 256, 0, stream>>>(
            xv, xr, xc, gidx, (const int*)nullptr, embs, out);
    }
}

// Round 7
// 493.860 us; speedup vs baseline: 1.1858x; 1.1858x over previous
//
#include <hip/hip_runtime.h>

// Problem constants (from reference)
#define NNZ_TOT    2097152
#define N_CELLS    4096
#define N_PRE      30000
#define NUM_HID    128
#define CHUNK      128                  // nnz per wave
#define N_WAVES    (NNZ_TOT / CHUNK)    // 16384 waves

// ---------------------------------------------------------------------------
// Precompute 1: g_arr[i] = gidx[xc[i]]  (fuse first indirection)
// ---------------------------------------------------------------------------
__global__ __launch_bounds__(256) void fuse_gidx_kernel(
    const int* __restrict__ xc, const int* __restrict__ gidx,
    int* __restrict__ g_arr)
{
    const int i = blockIdx.x * blockDim.x + threadIdx.x;
    if (i < NNZ_TOT) g_arr[i] = gidx[xc[i]];
}

// ---------------------------------------------------------------------------
// Precompute 2: bf16 copy of the embedding table (rows 512 B -> 256 B).
// Halves gather bytes AND lines/row; 7.7 MB table ~doubles L2 hit rate.
// ---------------------------------------------------------------------------
__device__ __forceinline__ unsigned short f2bf(float f) {
    union { float f; unsigned u; } c; c.f = f;
    unsigned u = c.u;
    u += 0x7fffu + ((u >> 16) & 1u);    // round-to-nearest-even
    return (unsigned short)(u >> 16);
}

__global__ __launch_bounds__(256) void convert_embs_kernel(
    const float* __restrict__ embs, unsigned short* __restrict__ ebf)
{
    const int i = blockIdx.x * blockDim.x + threadIdx.x;   // per 4 floats
    if (i * 4 < N_PRE * NUM_HID) {
        const float4 f = *reinterpret_cast<const float4*>(&embs[i * 4]);
        ushort4 o;
        o.x = f2bf(f.x); o.y = f2bf(f.y); o.z = f2bf(f.z); o.w = f2bf(f.w);
        *reinterpret_cast<ushort4*>(&ebf[i * 4]) = o;
    }
}

// ---------------------------------------------------------------------------
// Main kernel. One wave per 128-nnz chunk. Lane = (quad = lane>>4,
// sub = lane&15). sub owns dims [sub*8, sub*8+8) (16 B of bf16); quad
// selects one of 4 consecutive nnz. One global_load_dwordx4 per wave
// fetches 4 complete embedding rows.
//
// R5/R6 post-mortem: staging arrays (g[16]/v[16]) + select chains were
// promoted to LDS (16 KB block, 1.5e7 bank conflicts) and spilled to
// scratch (WRITE_SIZE 735 MB). This version has ZERO private arrays:
// control data is loaded per-lane (16-lane broadcast, coalescer dedups)
// and accumulators are two named float4s.
// ---------------------------------------------------------------------------
__device__ __forceinline__ void fma8(uint4 f, float vv, float4& a0, float4& a1) {
    a0.x = fmaf(vv, __uint_as_float(f.x << 16),         a0.x);
    a0.y = fmaf(vv, __uint_as_float(f.x & 0xffff0000u), a0.y);
    a0.z = fmaf(vv, __uint_as_float(f.y << 16),         a0.z);
    a0.w = fmaf(vv, __uint_as_float(f.y & 0xffff0000u), a0.w);
    a1.x = fmaf(vv, __uint_as_float(f.z << 16),         a1.x);
    a1.y = fmaf(vv, __uint_as_float(f.z & 0xffff0000u), a1.y);
    a1.z = fmaf(vv, __uint_as_float(f.w << 16),         a1.z);
    a1.w = fmaf(vv, __uint_as_float(f.w & 0xffff0000u), a1.w);
}

__device__ __forceinline__ void flushq(float* __restrict__ out, int row, int h8,
                                       float4& a0, float4& a1) {
    // Fire-and-forget atomics; 4-way quad collision HW-serialized at L2.
    float* o = &out[(long)row * NUM_HID + h8];
    atomicAdd(o + 0, a0.x); atomicAdd(o + 1, a0.y);
    atomicAdd(o + 2, a0.z); atomicAdd(o + 3, a0.w);
    atomicAdd(o + 4, a1.x); atomicAdd(o + 5, a1.y);
    atomicAdd(o + 6, a1.z); atomicAdd(o + 7, a1.w);
    a0 = make_float4(0.f, 0.f, 0.f, 0.f);
    a1 = make_float4(0.f, 0.f, 0.f, 0.f);
}

__global__ __launch_bounds__(256) void omics_bf16_kernel(
    const float*          __restrict__ xv,    // [NNZ] values
    const int*            __restrict__ xr,    // [NNZ] rows (sorted)
    const int*            __restrict__ g_arr, // [NNZ] fused gene ids
    const unsigned short* __restrict__ ebf,   // [N_PRE,128] bf16
    float*                __restrict__ out)   // [N_CELLS,128]
{
    const int wave = (blockIdx.x * blockDim.x + threadIdx.x) >> 6;
    const int lane = threadIdx.x & 63;
    const int sub  = lane & 15;
    const int quad = lane >> 4;
    const int base = __builtin_amdgcn_readfirstlane(wave * CHUNK);
    const int h8   = sub * 8;

    float4 a0 = make_float4(0.f, 0.f, 0.f, 0.f);
    float4 a1 = make_float4(0.f, 0.f, 0.f, 0.f);

    const int rF = xr[base];                   // uniform -> s_load
    const int rL = xr[base + CHUNK - 1];

    if (rF == rL) {
        // ---- fast path: whole chunk in one row (~75% of chunks) ----
        // Branchless; unroll 8 -> 8 independent gather chains in flight.
        #pragma unroll 8
        for (int it = 0; it < CHUNK; it += 4) {
            const int   idx = base + it + quad;
            const int   gg  = g_arr[idx];      // 4 distinct dwords/wave
            const float vv  = xv[idx];
            const uint4 f   = *reinterpret_cast<const uint4*>(
                &ebf[(long)gg * NUM_HID + h8]);
            fma8(f, vv, a0, a1);
        }
        flushq(out, rF, h8, a0, a1);
    } else {
        // ---- slow path: chunk crosses row boundary(ies). Each quad
        // tracks its OWN current row and flushes on change; branch is
        // quad-uniform (exec-mask predication), loads still hoistable.
        int cur = xr[base + quad];
        #pragma unroll 4
        for (int it = 0; it < CHUNK; it += 4) {
            const int idx = base + it + quad;
            const int r   = xr[idx];
            if (r != cur) { flushq(out, cur, h8, a0, a1); cur = r; }
            const int   gg = g_arr[idx];
            const float vv = xv[idx];
            const uint4 f  = *reinterpret_cast<const uint4*>(
                &ebf[(long)gg * NUM_HID + h8]);
            fma8(f, vv, a0, a1);
        }
        flushq(out, cur, h8, a0, a1);
    }
}

// ---------------------------------------------------------------------------
// Fallback (ws too small for bf16 table): fp32 chunk kernel (R4-class).
// ---------------------------------------------------------------------------
__device__ __forceinline__ void flush_row2(float* __restrict__ out, int row,
                                           int h, float2 acc) {
    float* o = &out[(long)row * NUM_HID + h];
    atomicAdd(o + 0, acc.x);
    atomicAdd(o + 1, acc.y);
}

template <bool PRE>
__global__ __launch_bounds__(256) void omics_fp32_kernel(
    const float* __restrict__ xv, const int* __restrict__ xr,
    const int* __restrict__ xc, const int* __restrict__ gidx,
    const int* __restrict__ g_arr, const float* __restrict__ embs,
    float* __restrict__ out)
{
    const int wave = (blockIdx.x * blockDim.x + threadIdx.x) >> 6;
    const int lane = threadIdx.x & 63;
    const int base = __builtin_amdgcn_readfirstlane(wave * CHUNK);
    const int h    = lane * 2;

    float2 acc = make_float2(0.f, 0.f);
    int cur = xr[base];
    for (int it = 0; it < CHUNK; it += 8) {
        const int i0 = base + it;
        #pragma unroll
        for (int j = 0; j < 8; ++j) {
            const int r = xr[i0 + j];
            if (r != cur) { flush_row2(out, cur, h, acc);
                            cur = r; acc = make_float2(0.f, 0.f); }
            const int   gg = PRE ? g_arr[i0 + j] : gidx[xc[i0 + j]];
            const float vv = xv[i0 + j];
            const float2 ff = *reinterpret_cast<const float2*>(
                &embs[(long)gg * NUM_HID + h]);
            acc.x = fmaf(vv, ff.x, acc.x);
            acc.y = fmaf(vv, ff.y, acc.y);
        }
    }
    flush_row2(out, cur, h, acc);
}

extern "C" void kernel_launch(void* const* d_in, const int* in_sizes, int n_in,
                              void* d_out, int out_size, void* d_ws, size_t ws_size,
                              hipStream_t stream) {
    const float* xv   = (const float*)d_in[0];
    const int*   xr   = (const int*)  d_in[1];
    const int*   xc   = (const int*)  d_in[2];
    const int*   gidx = (const int*)  d_in[3];
    const float* embs = (const float*)d_in[4];
    float*       out  = (float*)d_out;

    // Atomically accumulated -> zero first (harness poisons with 0xAA).
    hipMemsetAsync(out, 0, (size_t)out_size * sizeof(float), stream);

    const size_t g_bytes = (size_t)NNZ_TOT * sizeof(int);           // 8 MB
    const size_t e_bytes = (size_t)N_PRE * NUM_HID * 2;             // 7.7 MB
    const int    blocks  = (N_WAVES * 64) / 256;                    // 4096

    if (ws_size >= g_bytes + e_bytes) {
        int*            g_arr = (int*)d_ws;
        unsigned short* ebf   = (unsigned short*)((char*)d_ws + g_bytes);
        fuse_gidx_kernel<<<(NNZ_TOT + 255) / 256, 256, 0, stream>>>(
            xc, gidx, g_arr);
        convert_embs_kernel<<<(N_PRE * NUM_HID / 4 + 255) / 256, 256, 0, stream>>>(
            embs, ebf);
        omics_bf16_kernel<<<blocks, 256, 0, stream>>>(
            xv, xr, g_arr, ebf, out);
    } else if (ws_size >= g_bytes) {
        int* g_arr = (int*)d_ws;
        fuse_gidx_kernel<<<(NNZ_TOT + 255) / 256, 256, 0, stream>>>(
            xc, gidx, g_arr);
        omics_fp32_kernel<true><<<blocks, 256, 0, stream>>>(
            xv, xr, xc, gidx, g_arr, embs, out);
    } else {
        omics_fp32_kernel<false><<<blocks, 256, 0, stream>>>(
            xv, xr, xc, gidx, (const int*)nullptr, embs, out);
    }
}

// Round 8
// 137.121 us; speedup vs baseline: 4.2709x; 3.6016x over previous
//
#include <hip/hip_runtime.h>

// Problem constants (from reference)
#define NNZ_TOT    2097152
#define N_CELLS    4096
#define N_PRE      30000
#define NUM_HID    128

// ---------------------------------------------------------------------------
// Precompute 1: g_arr[i] = gidx[xc[i]]  (fuse first indirection)
// ---------------------------------------------------------------------------
__global__ __launch_bounds__(256) void fuse_gidx_kernel(
    const int* __restrict__ xc, const int* __restrict__ gidx,
    int* __restrict__ g_arr)
{
    const int i = blockIdx.x * blockDim.x + threadIdx.x;
    if (i < NNZ_TOT) g_arr[i] = gidx[xc[i]];
}

// ---------------------------------------------------------------------------
// Precompute 2: bf16 copy of the embedding table (rows 512 B -> 256 B).
// R7 proved this makes the table L2-resident (FETCH_SIZE 250 -> 41 MB).
// ---------------------------------------------------------------------------
__device__ __forceinline__ unsigned short f2bf(float f) {
    union { float f; unsigned u; } c; c.f = f;
    unsigned u = c.u;
    u += 0x7fffu + ((u >> 16) & 1u);    // round-to-nearest-even
    return (unsigned short)(u >> 16);
}

__global__ __launch_bounds__(256) void convert_embs_kernel(
    const float* __restrict__ embs, unsigned short* __restrict__ ebf)
{
    const int i = blockIdx.x * blockDim.x + threadIdx.x;   // per 4 floats
    if (i * 4 < N_PRE * NUM_HID) {
        const float4 f = *reinterpret_cast<const float4*>(&embs[i * 4]);
        ushort4 o;
        o.x = f2bf(f.x); o.y = f2bf(f.y); o.z = f2bf(f.z); o.w = f2bf(f.w);
        *reinterpret_cast<ushort4*>(&ebf[i * 4]) = o;
    }
}

// ---------------------------------------------------------------------------
// Precompute 3: CSR row pointers. rp[r] = lower_bound(xr, r), r in [0,4096].
// ---------------------------------------------------------------------------
__global__ __launch_bounds__(256) void row_ptr_kernel(
    const int* __restrict__ xr, int* __restrict__ rp)
{
    const int r = blockIdx.x * blockDim.x + threadIdx.x;
    if (r <= N_CELLS) {
        int lo = 0, hi = NNZ_TOT;
        while (lo < hi) {
            const int mid = (lo + hi) >> 1;
            if (xr[mid] < r) lo = mid + 1; else hi = mid;
        }
        rp[r] = lo;
    }
}

// ---------------------------------------------------------------------------
// Main kernel: ONE WAVE PER OUTPUT ROW -- zero atomics, zero memset.
// Lane = (quad = lane>>4, sub = lane&15). sub owns dims [sub*8, sub*8+8)
// (16 B of bf16); quad selects one of 4 consecutive nnz, so one
// global_load_dwordx4 fetches 4 complete embedding rows (2 lines/nnz).
// Main loop: 16 nnz per straight-line group = 4 independent gathers in
// flight; two accumulator pairs halve the FMA dependency chain.
// End: shfl_xor(16/32) cross-quad reduction, quad 0 plain-stores the row.
// R7 post-mortem: 10M device-scope atomics cost 325 MB of coherent-point
// writes and 419 us. This design has NO atomics at all.
// ---------------------------------------------------------------------------
__device__ __forceinline__ void fma8(uint4 f, float vv, float4& a0, float4& a1) {
    a0.x = fmaf(vv, __uint_as_float(f.x << 16),         a0.x);
    a0.y = fmaf(vv, __uint_as_float(f.x & 0xffff0000u), a0.y);
    a0.z = fmaf(vv, __uint_as_float(f.y << 16),         a0.z);
    a0.w = fmaf(vv, __uint_as_float(f.y & 0xffff0000u), a0.w);
    a1.x = fmaf(vv, __uint_as_float(f.z << 16),         a1.x);
    a1.y = fmaf(vv, __uint_as_float(f.z & 0xffff0000u), a1.y);
    a1.z = fmaf(vv, __uint_as_float(f.w << 16),         a1.z);
    a1.w = fmaf(vv, __uint_as_float(f.w & 0xffff0000u), a1.w);
}

__global__ __launch_bounds__(256) void omics_row_kernel(
    const float*          __restrict__ xv,    // [NNZ] values
    const int*            __restrict__ g_arr, // [NNZ] fused gene ids
    const int*            __restrict__ rp,    // [N_CELLS+1] row pointers
    const unsigned short* __restrict__ ebf,   // [N_PRE,128] bf16
    float*                __restrict__ out)   // [N_CELLS,128]
{
    const int wave = (blockIdx.x * blockDim.x + threadIdx.x) >> 6;
    const int lane = threadIdx.x & 63;
    const int sub  = lane & 15;
    const int quad = lane >> 4;
    const int r    = __builtin_amdgcn_readfirstlane(wave);
    if (r >= N_CELLS) return;

    const int lo = rp[r];
    const int hi = rp[r + 1];
    const int h8 = sub * 8;

    float4 a0 = make_float4(0.f, 0.f, 0.f, 0.f);
    float4 a1 = make_float4(0.f, 0.f, 0.f, 0.f);
    float4 b0 = make_float4(0.f, 0.f, 0.f, 0.f);
    float4 b1 = make_float4(0.f, 0.f, 0.f, 0.f);

    int i = lo;
    // ---- main body: 16 nnz per straight-line group (4 gathers in flight)
    for (; i + 16 <= hi; i += 16) {
        const int i0 = i + quad;
        const int g0 = g_arr[i0];      const float v0 = xv[i0];
        const int g1 = g_arr[i0 + 4];  const float v1 = xv[i0 + 4];
        const int g2 = g_arr[i0 + 8];  const float v2 = xv[i0 + 8];
        const int g3 = g_arr[i0 + 12]; const float v3 = xv[i0 + 12];

        const uint4 f0 = *reinterpret_cast<const uint4*>(&ebf[(long)g0 * NUM_HID + h8]);
        const uint4 f1 = *reinterpret_cast<const uint4*>(&ebf[(long)g1 * NUM_HID + h8]);
        const uint4 f2 = *reinterpret_cast<const uint4*>(&ebf[(long)g2 * NUM_HID + h8]);
        const uint4 f3 = *reinterpret_cast<const uint4*>(&ebf[(long)g3 * NUM_HID + h8]);

        fma8(f0, v0, a0, a1);
        fma8(f1, v1, b0, b1);
        fma8(f2, v2, a0, a1);
        fma8(f3, v3, b0, b1);
    }
    // ---- tail: up to 15 nnz, predicated by clamped index + zeroed value
    for (; i < hi; i += 4) {
        const int  idx = i + quad;
        const bool ok  = idx < hi;
        const int   gg = g_arr[ok ? idx : (hi - 1)];
        const float vv = ok ? xv[idx] : 0.f;
        const uint4 f  = *reinterpret_cast<const uint4*>(&ebf[(long)gg * NUM_HID + h8]);
        fma8(f, vv, a0, a1);
    }

    // merge the two accumulator pairs
    a0.x += b0.x; a0.y += b0.y; a0.z += b0.z; a0.w += b0.w;
    a1.x += b1.x; a1.y += b1.y; a1.z += b1.z; a1.w += b1.w;

    // cross-quad reduction (quads hold disjoint nnz subsets of the same row)
    a0.x += __shfl_xor(a0.x, 16); a0.x += __shfl_xor(a0.x, 32);
    a0.y += __shfl_xor(a0.y, 16); a0.y += __shfl_xor(a0.y, 32);
    a0.z += __shfl_xor(a0.z, 16); a0.z += __shfl_xor(a0.z, 32);
    a0.w += __shfl_xor(a0.w, 16); a0.w += __shfl_xor(a0.w, 32);
    a1.x += __shfl_xor(a1.x, 16); a1.x += __shfl_xor(a1.x, 32);
    a1.y += __shfl_xor(a1.y, 16); a1.y += __shfl_xor(a1.y, 32);
    a1.z += __shfl_xor(a1.z, 16); a1.z += __shfl_xor(a1.z, 32);
    a1.w += __shfl_xor(a1.w, 16); a1.w += __shfl_xor(a1.w, 32);

    if (quad == 0) {
        float* o = &out[(long)r * NUM_HID + h8];
        *reinterpret_cast<float4*>(o)     = a0;
        *reinterpret_cast<float4*>(o + 4) = a1;
    }
}

// ---------------------------------------------------------------------------
// Fallback (ws too small): fp32, one wave per row, binary search inline,
// plain stores (R2-class, known-passing ~139 us).
// ---------------------------------------------------------------------------
__global__ __launch_bounds__(256) void omics_fp32_row_kernel(
    const float* __restrict__ xv, const int* __restrict__ xr,
    const int* __restrict__ xc, const int* __restrict__ gidx,
    const float* __restrict__ embs, float* __restrict__ out)
{
    const int wave = (blockIdx.x * blockDim.x + threadIdx.x) >> 6;
    const int lane = threadIdx.x & 63;
    if (wave >= N_CELLS) return;
    int lo = 0, hi = NNZ_TOT;
    while (lo < hi) { int m = (lo + hi) >> 1; if (xr[m] < wave) lo = m + 1; else hi = m; }
    int lo2 = lo, hi2 = NNZ_TOT;
    while (lo2 < hi2) { int m = (lo2 + hi2) >> 1; if (xr[m] < wave + 1) lo2 = m + 1; else hi2 = m; }
    const int h = lane * 2;
    float2 acc = make_float2(0.f, 0.f);
    for (int i = lo; i < lo2; ++i) {
        const float v = xv[i];
        const int   g = gidx[xc[i]];
        const float2 f = *reinterpret_cast<const float2*>(&embs[(long)g * NUM_HID + h]);
        acc.x = fmaf(v, f.x, acc.x);
        acc.y = fmaf(v, f.y, acc.y);
    }
    *reinterpret_cast<float2*>(&out[(long)wave * NUM_HID + h]) = acc;
}

extern "C" void kernel_launch(void* const* d_in, const int* in_sizes, int n_in,
                              void* d_out, int out_size, void* d_ws, size_t ws_size,
                              hipStream_t stream) {
    const float* xv   = (const float*)d_in[0];
    const int*   xr   = (const int*)  d_in[1];
    const int*   xc   = (const int*)  d_in[2];
    const int*   gidx = (const int*)  d_in[3];
    const float* embs = (const float*)d_in[4];
    float*       out  = (float*)d_out;

    const size_t rp_bytes = ((size_t)(N_CELLS + 1) * sizeof(int) + 255) & ~255;
    const size_t g_bytes  = (size_t)NNZ_TOT * sizeof(int);          // 8 MB
    const size_t e_bytes  = (size_t)N_PRE * NUM_HID * 2;            // 7.7 MB

    if (ws_size >= rp_bytes + g_bytes + e_bytes) {
        int*            rp    = (int*)d_ws;
        int*            g_arr = (int*)((char*)d_ws + rp_bytes);
        unsigned short* ebf   = (unsigned short*)((char*)d_ws + rp_bytes + g_bytes);

        row_ptr_kernel<<<(N_CELLS + 256) / 256, 256, 0, stream>>>(xr, rp);
        fuse_gidx_kernel<<<(NNZ_TOT + 255) / 256, 256, 0, stream>>>(xc, gidx, g_arr);
        convert_embs_kernel<<<(N_PRE * NUM_HID / 4 + 255) / 256, 256, 0, stream>>>(embs, ebf);

        // one wave per row: 4096 waves = 1024 blocks x 256 threads
        omics_row_kernel<<<(N_CELLS * 64) / 256, 256, 0, stream>>>(
            xv, g_arr, rp, ebf, out);
    } else {
        omics_fp32_row_kernel<<<(N_CELLS * 64) / 256, 256, 0, stream>>>(
            xv, xr, xc, gidx, embs, out);
    }
}